// Round 6
// baseline (378.634 us; speedup 1.0000x reference)
//
#include <hip/hip_runtime.h>

typedef float f4v __attribute__((ext_vector_type(4)));
typedef short s8v __attribute__((ext_vector_type(8)));

#define TT 128
#define II 28
#define HH 200
#define BB 16        // batch rows per block
#define NT 320       // 5 waves
#define CH 8         // timesteps per chunk
#define KX 224       // combined-K offset of x block
#define NCH (TT / CH)

template <int N> struct IC { static constexpr int value = N; };

// round-half-up f32->bf16 pair packed to one dword
__device__ __forceinline__ unsigned pk_hu(float a, float b) {
    unsigned ua = __builtin_bit_cast(unsigned, a) + 0x8000u;
    unsigned ub = __builtin_bit_cast(unsigned, b) + 0x8000u;
    return __builtin_amdgcn_perm(ub, ua, 0x07060302);
}
__device__ __forceinline__ short f2bf(float f) {
    return (short)((__builtin_bit_cast(unsigned, f) + 0x8000u) >> 16);
}
__device__ __forceinline__ float bf2f(short s) {
    return __builtin_bit_cast(float, ((unsigned)(unsigned short)s) << 16);
}

// lgkm-only barrier: h ds_writes visible, chunk-DMA vmcnt stays in flight
#define STEP_BAR() asm volatile("s_waitcnt lgkmcnt(0)\n\ts_barrier" ::: "memory")
// vmcnt-inclusive barrier: additionally publishes every wave's DMA completions
#define VSTEP_BAR() asm volatile("s_waitcnt vmcnt(0) lgkmcnt(0)\n\ts_barrier" ::: "memory")

__global__ __launch_bounds__(NT, 3)
void rnn_r12(const float* __restrict__ x,
             const float* __restrict__ W_ih,
             const float* __restrict__ W_hh,
             const float* __restrict__ b_ih,
             const float* __restrict__ b_hh,
             const float* __restrict__ W_fc,
             const float* __restrict__ b_fc,
             float* __restrict__ out)
{
    // MFMA-fragment-order LDS (r11 layout, zero-conflict reads).
    // LDS: Hf 14336 + Xf 16384 + Xl 14336 = 45056 B -> 2 blocks/CU (90 KB of 160 KB pool)
    __shared__ __align__(16) short Hf[2][7][512];     // bf16 h fragments; k=200..223 zero
    __shared__ __align__(16) short Xf[2][CH][512];    // bf16 x fragments (dbuf); k=252,253 bias
    __shared__ __align__(16) float Xl[CH * BB * II];  // raw f32 x staging, [t][r][c]

    const int tid  = threadIdx.x;
    const int lane = tid & 63;
    const int q    = lane >> 4;
    const int lr   = lane & 15;
    const int wave = __builtin_amdgcn_readfirstlane(tid >> 6);
    const int b0   = blockIdx.x * BB;

    // j-tile split over 5 waves: {3,3,3,2,2} of 13 tiles (16 j each)
    const int ntl  = (wave < 3) ? 3 : 2;
    const int jtb  = (wave < 3) ? 3 * wave : 9 + 2 * (wave - 3);

    // ---- x DMA: 14 wave-issues of 64x16B per chunk; waves 0-3: 3, wave 4: 2
    const int nIss = (wave < 4) ? 3 : 2;
    const int e0   = (wave < 4) ? 3 * wave : 12;
    unsigned xoff[3];
    #pragma unroll
    for (int k = 0; k < 3; ++k) {
        const int e  = e0 + k;
        const int m  = (e << 6) + lane;      // 16B-chunk index 0..895
        const int tl = m / 112;              // 112 chunks per timestep (16r*28c/4)
        const int rm = m - tl * 112;
        const int r  = rm / 7;
        const int c4 = rm - r * 7;
        xoff[k] = (unsigned)(((((b0 + r) * TT + tl) * II) + c4 * 4) * 4);  // bytes
    }
    auto issue_dma = [&](int c) {
        #pragma unroll
        for (int k = 0; k < 3; ++k) {
            if (k < nIss) {
                const char* src = (const char*)x + (xoff[k] + (unsigned)c * (CH * II * 4));
                float* dst = &Xl[(e0 + k) * 256];
                __builtin_amdgcn_global_load_lds(
                    (const __attribute__((address_space(1))) void*)src,
                    (__attribute__((address_space(3))) void*)dst, 16, 0, 0);
            }
        }
    };

    // pre-pass: Xl f32 -> Xf[tc&1] bf16 fragments (224 threads x 16 floats)
    // pair (c=2cp,2cp+1) of row r, step t -> fragment dword t*256 + 64*(cp>>2) + 4*r + (cp&3)
    auto prepass = [&](int tc) {
        if (tid < 224) {
            const f4v v0 = *(const f4v*)&Xl[tid * 16];
            const f4v v1 = *(const f4v*)&Xl[tid * 16 + 4];
            const f4v v2 = *(const f4v*)&Xl[tid * 16 + 8];
            const f4v v3 = *(const f4v*)&Xl[tid * 16 + 12];
            const unsigned d[8] = { pk_hu(v0.x, v0.y), pk_hu(v0.z, v0.w),
                                    pk_hu(v1.x, v1.y), pk_hu(v1.z, v1.w),
                                    pk_hu(v2.x, v2.y), pk_hu(v2.z, v2.w),
                                    pk_hu(v3.x, v3.y), pk_hu(v3.z, v3.w) };
            int* dstb = ((int*)Xf) + (tc & 1) * 2048;
            #pragma unroll
            for (int dk = 0; dk < 8; ++dk) {
                const int kk = tid * 8 + dk;        // packed-dword index
                const int t  = kk / 224;            // 224 dwords per timestep
                const int k2 = kk - t * 224;
                const int r  = k2 / 14;
                const int cp = k2 - r * 14;
                dstb[t * 256 + 64 * (cp >> 2) + 4 * r + (cp & 3)] = (int)d[dk];
            }
        }
    };

    issue_dma(0);

    // ---- W~ fragments (AGPR-backed): W~[j][k] = W_hh (k<200) | W_ih (224<=k<252)
    //      | bf16(b_ih+b_hh) (k==252) | bf16(bias residual) (k==253)
    s8v Af[3][8];
    #pragma unroll
    for (int u = 0; u < 3; ++u) {
        const int j = 16 * (jtb + u) + lr;
        #pragma unroll
        for (int kc = 0; kc < 8; ++kc) {
            union { short s[8]; s8v v; } tv;
            #pragma unroll
            for (int i = 0; i < 8; ++i) {
                const int k = 32 * kc + 8 * q + i;
                float w = 0.0f;
                if (u < ntl && j < HH) {
                    if (k < HH)                     w = W_hh[j * HH + k];
                    else if (k >= KX && k < KX+II)  w = W_ih[j * II + (k - KX)];
                    else if (k == KX + II) {
                        w = b_ih[j] + b_hh[j];
                    } else if (k == KX + II + 1) {
                        const float bs = b_ih[j] + b_hh[j];
                        w = bs - bf2f(f2bf(bs));   // residual of bf16-rounded bias
                    }
                }
                tv.s[i] = f2bf(w);
            }
            Af[u][kc] = tv.v;
        }
    }

    // zero Hf; Xf init: bias dwords (frag dword %256 >=194, %4==2 -> k=252,253) = 1.0,1.0
    for (int i = tid; i < 2 * 7 * 512 / 2; i += NT) ((int*)Hf)[i] = 0;
    for (int i = tid; i < 2 * CH * 512 / 2; i += NT)
        ((int*)Xf)[i] = (((i & 255) >= 194) && ((i & 3) == 2)) ? 0x3f803f80 : 0;

    // retire-write addresses (wave-uniform jt, per-lane q/lr)
    short* st[3];
    #pragma unroll
    for (int u = 0; u < 3; ++u) {
        const int jw = 16 * (jtb + u) + 4 * q;
        st[u] = &Hf[0][jw >> 5][(16 * ((jw >> 3) & 3) + lr) * 8 + (jw & 7)];
    }
    const int HFH = 7 * 512;   // shorts per h buffer

    __syncthreads();   // DMA(0) drained (vmcnt+barrier), init visible
    prepass(0);        // fill Xf[0]
    STEP_BAR();        // Xf[0] visible; all Xl reads retired
    issue_dma(1);

    const f4v Z = {0.f, 0.f, 0.f, 0.f};

    auto chunk = [&](int c, auto NTC) {
        constexpr int NTL = decltype(NTC)::value;
        const short* xbase = &Xf[c & 1][0][0];
        #pragma unroll
        for (int s = 0; s < CH; ++s) {
            const int pb = s & 1;   // global t = c*8+s, c*8 even -> parity = s&1
            const short* hf = &Hf[pb][0][lane * 8];
            const s8v xb = *(const s8v*)&xbase[s * 512 + lane * 8];
            s8v g0 = *(const s8v*)(hf);           // kc0
            s8v g1 = *(const s8v*)(hf + 512);     // kc1
            s8v g2 = *(const s8v*)(hf + 1024);    // kc2
            s8v g3 = *(const s8v*)(hf + 1536);    // kc3
            f4v a0, a1, a2;
            // x-column MFMAs (register-fed), then kc0..kc6, u-interleaved (dep dist NTL)
            a0 = __builtin_amdgcn_mfma_f32_16x16x32_bf16(Af[0][7], xb, Z, 0, 0, 0);
            if constexpr (NTL > 1) a1 = __builtin_amdgcn_mfma_f32_16x16x32_bf16(Af[1][7], xb, Z, 0, 0, 0);
            if constexpr (NTL > 2) a2 = __builtin_amdgcn_mfma_f32_16x16x32_bf16(Af[2][7], xb, Z, 0, 0, 0);
            a0 = __builtin_amdgcn_mfma_f32_16x16x32_bf16(Af[0][0], g0, a0, 0, 0, 0);
            if constexpr (NTL > 1) a1 = __builtin_amdgcn_mfma_f32_16x16x32_bf16(Af[1][0], g0, a1, 0, 0, 0);
            if constexpr (NTL > 2) a2 = __builtin_amdgcn_mfma_f32_16x16x32_bf16(Af[2][0], g0, a2, 0, 0, 0);
            g0 = *(const s8v*)(hf + 2048);        // kc4
            a0 = __builtin_amdgcn_mfma_f32_16x16x32_bf16(Af[0][1], g1, a0, 0, 0, 0);
            if constexpr (NTL > 1) a1 = __builtin_amdgcn_mfma_f32_16x16x32_bf16(Af[1][1], g1, a1, 0, 0, 0);
            if constexpr (NTL > 2) a2 = __builtin_amdgcn_mfma_f32_16x16x32_bf16(Af[2][1], g1, a2, 0, 0, 0);
            g1 = *(const s8v*)(hf + 2560);        // kc5
            a0 = __builtin_amdgcn_mfma_f32_16x16x32_bf16(Af[0][2], g2, a0, 0, 0, 0);
            if constexpr (NTL > 1) a1 = __builtin_amdgcn_mfma_f32_16x16x32_bf16(Af[1][2], g2, a1, 0, 0, 0);
            if constexpr (NTL > 2) a2 = __builtin_amdgcn_mfma_f32_16x16x32_bf16(Af[2][2], g2, a2, 0, 0, 0);
            g2 = *(const s8v*)(hf + 3072);        // kc6
            a0 = __builtin_amdgcn_mfma_f32_16x16x32_bf16(Af[0][3], g3, a0, 0, 0, 0);
            if constexpr (NTL > 1) a1 = __builtin_amdgcn_mfma_f32_16x16x32_bf16(Af[1][3], g3, a1, 0, 0, 0);
            if constexpr (NTL > 2) a2 = __builtin_amdgcn_mfma_f32_16x16x32_bf16(Af[2][3], g3, a2, 0, 0, 0);
            a0 = __builtin_amdgcn_mfma_f32_16x16x32_bf16(Af[0][4], g0, a0, 0, 0, 0);
            if constexpr (NTL > 1) a1 = __builtin_amdgcn_mfma_f32_16x16x32_bf16(Af[1][4], g0, a1, 0, 0, 0);
            if constexpr (NTL > 2) a2 = __builtin_amdgcn_mfma_f32_16x16x32_bf16(Af[2][4], g0, a2, 0, 0, 0);
            a0 = __builtin_amdgcn_mfma_f32_16x16x32_bf16(Af[0][5], g1, a0, 0, 0, 0);
            if constexpr (NTL > 1) a1 = __builtin_amdgcn_mfma_f32_16x16x32_bf16(Af[1][5], g1, a1, 0, 0, 0);
            if constexpr (NTL > 2) a2 = __builtin_amdgcn_mfma_f32_16x16x32_bf16(Af[2][5], g1, a2, 0, 0, 0);
            a0 = __builtin_amdgcn_mfma_f32_16x16x32_bf16(Af[0][6], g2, a0, 0, 0, 0);
            if constexpr (NTL > 1) a1 = __builtin_amdgcn_mfma_f32_16x16x32_bf16(Af[1][6], g2, a1, 0, 0, 0);
            if constexpr (NTL > 2) a2 = __builtin_amdgcn_mfma_f32_16x16x32_bf16(Af[2][6], g2, a2, 0, 0, 0);
            // retire: relu -> bf16 -> Hf[pb^1] (fragment-order, 4 dwords/bank)
            {
                const int wo = (pb ^ 1) * HFH;
                int2 hv;
                hv.x = (int)pk_hu(fmaxf(a0.x, 0.f), fmaxf(a0.y, 0.f));
                hv.y = (int)pk_hu(fmaxf(a0.z, 0.f), fmaxf(a0.w, 0.f));
                *(int2*)(st[0] + wo) = hv;
                if constexpr (NTL > 1) {
                    hv.x = (int)pk_hu(fmaxf(a1.x, 0.f), fmaxf(a1.y, 0.f));
                    hv.y = (int)pk_hu(fmaxf(a1.z, 0.f), fmaxf(a1.w, 0.f));
                    *(int2*)(st[1] + wo) = hv;
                }
                if constexpr (NTL > 2) {
                    hv.x = (int)pk_hu(fmaxf(a2.x, 0.f), fmaxf(a2.y, 0.f));
                    hv.y = (int)pk_hu(fmaxf(a2.z, 0.f), fmaxf(a2.w, 0.f));
                    *(int2*)(st[2] + wo) = hv;
                }
            }
            // pipeline plumbing (wave-uniform, compile-time s):
            if (s == 4 && c + 1 < NCH) prepass(c + 1);
            if (s == 5 && c + 2 < NCH) issue_dma(c + 2);
            if (s == 3) VSTEP_BAR();
            else        STEP_BAR();
        }
    };

    #pragma unroll 1
    for (int c = 0; c < NCH; ++c) {
        if (ntl == 3) chunk(c, IC<3>{});
        else          chunk(c, IC<2>{});
    }

    __syncthreads();
    // ---- FC epilogue: h_T (bf16) in Hf[0] (t=127 wrote pb^1 = 0)
    if (tid < BB * 10) {
        const int o = tid >> 4, r = tid & 15;
        const float* wrow = W_fc + o * HH;
        float acc = b_fc[o];
        #pragma unroll 1
        for (int kb = 0; kb < 25; ++kb) {
            const s8v hv = *(const s8v*)&Hf[0][kb >> 2][(16 * (kb & 3) + r) * 8];
            const f4v w0 = *(const f4v*)(wrow + kb * 8);
            const f4v w1 = *(const f4v*)(wrow + kb * 8 + 4);
            acc = fmaf(bf2f(hv[0]), w0.x, acc);
            acc = fmaf(bf2f(hv[1]), w0.y, acc);
            acc = fmaf(bf2f(hv[2]), w0.z, acc);
            acc = fmaf(bf2f(hv[3]), w0.w, acc);
            acc = fmaf(bf2f(hv[4]), w1.x, acc);
            acc = fmaf(bf2f(hv[5]), w1.y, acc);
            acc = fmaf(bf2f(hv[6]), w1.z, acc);
            acc = fmaf(bf2f(hv[7]), w1.w, acc);
        }
        __builtin_nontemporal_store(acc, &out[(long)(b0 + r) * 10 + o]);
    }
}

extern "C" void kernel_launch(void* const* d_in, const int* in_sizes, int n_in,
                              void* d_out, int out_size, void* d_ws, size_t ws_size,
                              hipStream_t stream) {
    const float* x    = (const float*)d_in[0];
    const float* W_ih = (const float*)d_in[1];
    const float* W_hh = (const float*)d_in[2];
    const float* b_ih = (const float*)d_in[3];
    const float* b_hh = (const float*)d_in[4];
    const float* W_fc = (const float*)d_in[5];
    const float* b_fc = (const float*)d_in[6];
    float* out = (float*)d_out;

    rnn_r12<<<dim3(8192 / BB), dim3(NT), 0, stream>>>(
        x, W_ih, W_hh, b_ih, b_hh, W_fc, b_fc, out);
}

// Round 7
// 277.356 us; speedup vs baseline: 1.3652x; 1.3652x over previous
//
#include <hip/hip_runtime.h>

typedef float f4v __attribute__((ext_vector_type(4)));
typedef short s8v __attribute__((ext_vector_type(8)));

#define TT 128
#define II 28
#define HH 200
#define BB 16        // batch rows per block
#define NT 512       // 8 waves
#define CH 8         // timesteps per chunk
#define KX 224       // combined-K offset of x block
#define NCH (TT / CH)

template <bool B> struct BC { static constexpr bool value = B; };

// round-half-up f32->bf16 pair packed to one dword
__device__ __forceinline__ unsigned pk_hu(float a, float b) {
    unsigned ua = __builtin_bit_cast(unsigned, a) + 0x8000u;
    unsigned ub = __builtin_bit_cast(unsigned, b) + 0x8000u;
    return __builtin_amdgcn_perm(ub, ua, 0x07060302);
}
__device__ __forceinline__ short f2bf(float f) {
    return (short)((__builtin_bit_cast(unsigned, f) + 0x8000u) >> 16);
}
__device__ __forceinline__ float bf2f(short s) {
    return __builtin_bit_cast(float, ((unsigned)(unsigned short)s) << 16);
}

// lgkm-only barrier: h ds_writes visible, chunk-DMA vmcnt stays in flight
#define STEP_BAR() asm volatile("s_waitcnt lgkmcnt(0)\n\ts_barrier" ::: "memory")
// vmcnt-inclusive barrier: additionally publishes every wave's DMA completions
#define VSTEP_BAR() asm volatile("s_waitcnt vmcnt(0) lgkmcnt(0)\n\ts_barrier" ::: "memory")

__global__ __launch_bounds__(NT, 4)
void rnn_r13(const float* __restrict__ x,
             const float* __restrict__ W_ih,
             const float* __restrict__ W_hh,
             const float* __restrict__ b_ih,
             const float* __restrict__ b_hh,
             const float* __restrict__ W_fc,
             const float* __restrict__ b_fc,
             float* __restrict__ out)
{
    // MFMA-fragment-order LDS (r11 layout, zero-conflict reads).
    // LDS: Hf 14336 + Xf 16384 + Xl 14336 = 45056 B -> 2 blocks/CU
    __shared__ __align__(16) short Hf[2][7][512];     // bf16 h fragments; k=200..223 zero
    __shared__ __align__(16) short Xf[2][CH][512];    // bf16 x fragments (dbuf); k=252,253 bias
    __shared__ __align__(16) float Xl[CH * BB * II];  // raw f32 x staging, [t][r][c]

    const int tid  = threadIdx.x;
    const int lane = tid & 63;
    const int q    = lane >> 4;
    const int lr   = lane & 15;
    const int wave = __builtin_amdgcn_readfirstlane(tid >> 6);
    const int b0   = blockIdx.x * BB;

    // j-tile split: waves 0-4 own 2 tiles, waves 5-7 own 1 (13 tiles of 16 j)
    const bool two = (wave < 5);
    const int jt0  = two ? 2 * wave : 10 + (wave - 5);
    const int jt1  = two ? 2 * wave + 1 : 13;   // 13 unused on light path

    // ---- x DMA: 14 wave-issues of 64x16B per chunk; waves 0-5: 2, waves 6-7: 1
    const int nIss = (wave < 6) ? 2 : 1;
    const int e0   = (wave < 6) ? 2 * wave : 12 + (wave - 6);
    unsigned xoff[2];
    #pragma unroll
    for (int k = 0; k < 2; ++k) {
        const int e  = e0 + k;
        const int m  = (e << 6) + lane;      // 16B-chunk index 0..895
        const int tl = m / 112;              // 112 chunks per timestep (16r*28c/4)
        const int rm = m - tl * 112;
        const int r  = rm / 7;
        const int c4 = rm - r * 7;
        xoff[k] = (unsigned)(((((b0 + r) * TT + tl) * II) + c4 * 4) * 4);  // bytes
    }
    auto issue_dma = [&](int c) {
        #pragma unroll
        for (int k = 0; k < 2; ++k) {
            if (k < nIss) {
                const char* src = (const char*)x + (xoff[k] + (unsigned)c * (CH * II * 4));
                float* dst = &Xl[(e0 + k) * 256];
                __builtin_amdgcn_global_load_lds(
                    (const __attribute__((address_space(1))) void*)src,
                    (__attribute__((address_space(3))) void*)dst, 16, 0, 0);
            }
        }
    };

    // pre-pass: Xl f32 -> Xf[tc&1] bf16 fragments (448 threads x 8 floats)
    auto prepass = [&](int tc) {
        if (tid < 448) {
            const f4v v0 = *(const f4v*)&Xl[tid * 8];
            const f4v v1 = *(const f4v*)&Xl[tid * 8 + 4];
            const unsigned d[4] = { pk_hu(v0.x, v0.y), pk_hu(v0.z, v0.w),
                                    pk_hu(v1.x, v1.y), pk_hu(v1.z, v1.w) };
            int* dstb = ((int*)Xf) + (tc & 1) * 2048;
            #pragma unroll
            for (int dk = 0; dk < 4; ++dk) {
                const int kk = tid * 4 + dk;        // packed-dword index
                const int t  = kk / 224;            // 224 dwords per timestep
                const int k2 = kk - t * 224;
                const int r  = k2 / 14;
                const int cp = k2 - r * 14;
                dstb[t * 256 + 64 * (cp >> 2) + 4 * r + (cp & 3)] = (int)d[dk];
            }
        }
    };

    issue_dma(0);

    // ---- W~ fragments (AGPR-backed): W~[j][k] = W_hh (k<200) | W_ih (224<=k<252)
    //      | bf16(b_ih+b_hh) (k==252) | bf16(bias residual) (k==253)
    s8v Af[2][8];
    #pragma unroll
    for (int u = 0; u < 2; ++u) {
        const int j = 16 * (u ? jt1 : jt0) + lr;
        #pragma unroll
        for (int kc = 0; kc < 8; ++kc) {
            union { short s[8]; s8v v; } tv;
            #pragma unroll
            for (int i = 0; i < 8; ++i) {
                const int k = 32 * kc + 8 * q + i;
                float w = 0.0f;
                if (j < HH) {
                    if (k < HH)                     w = W_hh[j * HH + k];
                    else if (k >= KX && k < KX+II)  w = W_ih[j * II + (k - KX)];
                    else if (k == KX + II) {
                        w = b_ih[j] + b_hh[j];
                    } else if (k == KX + II + 1) {
                        const float bs = b_ih[j] + b_hh[j];
                        w = bs - bf2f(f2bf(bs));   // residual of bf16-rounded bias
                    }
                }
                tv.s[i] = f2bf(w);
            }
            Af[u][kc] = tv.v;
        }
    }

    // zero Hf; Xf init: bias dwords (frag dword %256 >=194, %4==2 -> k=252,253) = 1.0,1.0
    for (int i = tid; i < 2 * 7 * 512 / 2; i += NT) ((int*)Hf)[i] = 0;
    for (int i = tid; i < 2 * CH * 512 / 2; i += NT)
        ((int*)Xf)[i] = (((i & 255) >= 194) && ((i & 3) == 2)) ? 0x3f803f80 : 0;

    // retire-write addresses (wave-uniform jt, per-lane q/lr)
    const int j0w = 16 * jt0 + 4 * q;
    short* st0 = &Hf[0][j0w >> 5][(16 * ((j0w >> 3) & 3) + lr) * 8 + (j0w & 7)];
    const int j1w = 16 * jt1 + 4 * q;
    short* st1 = &Hf[0][j1w >> 5][(16 * ((j1w >> 3) & 3) + lr) * 8 + (j1w & 7)];
    const int HFH = 7 * 512;   // shorts per h buffer

    __syncthreads();   // DMA(0) drained (vmcnt+barrier), init visible
    prepass(0);        // fill Xf[0]
    STEP_BAR();        // Xf[0] visible; all Xl reads retired
    issue_dma(1);

    // anti-phase stagger: co-resident blocks are b and b+256 (round-robin over
    // 256 CUs). Offset the second set by ~half a step so the two blocks'
    // read/MFMA/retire phases interleave on complementary pipes.
    if ((blockIdx.x >> 8) & 1) asm volatile("s_sleep 23");

    const f4v Z = {0.f, 0.f, 0.f, 0.f};
    f4v a0, a1;   // carried accumulators: seeded with x(t)-contribution pre-barrier

    // prologue seed for t=0 (Xf[0][0] visible after STEP_BAR above)
    {
        const s8v xb = *(const s8v*)&Xf[0][0][lane * 8];
        a0 = __builtin_amdgcn_mfma_f32_16x16x32_bf16(Af[0][7], xb, Z, 0, 0, 0);
        if (two) a1 = __builtin_amdgcn_mfma_f32_16x16x32_bf16(Af[1][7], xb, Z, 0, 0, 0);
    }
    STEP_BAR();

    auto chunk = [&](int c, auto TWOC) {
        constexpr bool TWO = decltype(TWOC)::value;
        #pragma unroll
        for (int s = 0; s < CH; ++s) {
            const int pb = s & 1;   // global t = c*8+s, parity = s&1
            const short* hf = &Hf[pb][0][lane * 8];
            if constexpr (TWO) {
                s8v g0 = *(const s8v*)(hf);
                s8v g1 = *(const s8v*)(hf + 512);
                s8v g2 = *(const s8v*)(hf + 1024);
                s8v g3 = *(const s8v*)(hf + 1536);
                a0 = __builtin_amdgcn_mfma_f32_16x16x32_bf16(Af[0][0], g0, a0, 0, 0, 0);
                a1 = __builtin_amdgcn_mfma_f32_16x16x32_bf16(Af[1][0], g0, a1, 0, 0, 0);
                g0 = *(const s8v*)(hf + 2048);
                a0 = __builtin_amdgcn_mfma_f32_16x16x32_bf16(Af[0][1], g1, a0, 0, 0, 0);
                a1 = __builtin_amdgcn_mfma_f32_16x16x32_bf16(Af[1][1], g1, a1, 0, 0, 0);
                g1 = *(const s8v*)(hf + 2560);
                a0 = __builtin_amdgcn_mfma_f32_16x16x32_bf16(Af[0][2], g2, a0, 0, 0, 0);
                a1 = __builtin_amdgcn_mfma_f32_16x16x32_bf16(Af[1][2], g2, a1, 0, 0, 0);
                g2 = *(const s8v*)(hf + 3072);
                a0 = __builtin_amdgcn_mfma_f32_16x16x32_bf16(Af[0][3], g3, a0, 0, 0, 0);
                a1 = __builtin_amdgcn_mfma_f32_16x16x32_bf16(Af[1][3], g3, a1, 0, 0, 0);
                a0 = __builtin_amdgcn_mfma_f32_16x16x32_bf16(Af[0][4], g0, a0, 0, 0, 0);
                a1 = __builtin_amdgcn_mfma_f32_16x16x32_bf16(Af[1][4], g0, a1, 0, 0, 0);
                a0 = __builtin_amdgcn_mfma_f32_16x16x32_bf16(Af[0][5], g1, a0, 0, 0, 0);
                a1 = __builtin_amdgcn_mfma_f32_16x16x32_bf16(Af[1][5], g1, a1, 0, 0, 0);
                a0 = __builtin_amdgcn_mfma_f32_16x16x32_bf16(Af[0][6], g2, a0, 0, 0, 0);
                a1 = __builtin_amdgcn_mfma_f32_16x16x32_bf16(Af[1][6], g2, a1, 0, 0, 0);
            } else {
                // light wave: a0 carries x+kc0..kc2; a1 = kc3..kc6; merge at retire
                s8v g0 = *(const s8v*)(hf);           // kc0
                s8v g1 = *(const s8v*)(hf + 1536);    // kc3
                s8v g2 = *(const s8v*)(hf + 2048);    // kc4
                s8v g3 = *(const s8v*)(hf + 2560);    // kc5
                a1 = __builtin_amdgcn_mfma_f32_16x16x32_bf16(Af[0][3], g1, Z, 0, 0, 0);
                g1 = *(const s8v*)(hf + 512);         // kc1
                a0 = __builtin_amdgcn_mfma_f32_16x16x32_bf16(Af[0][0], g0, a0, 0, 0, 0);
                g0 = *(const s8v*)(hf + 1024);        // kc2
                a1 = __builtin_amdgcn_mfma_f32_16x16x32_bf16(Af[0][4], g2, a1, 0, 0, 0);
                g2 = *(const s8v*)(hf + 3072);        // kc6
                a0 = __builtin_amdgcn_mfma_f32_16x16x32_bf16(Af[0][1], g1, a0, 0, 0, 0);
                a1 = __builtin_amdgcn_mfma_f32_16x16x32_bf16(Af[0][5], g3, a1, 0, 0, 0);
                a0 = __builtin_amdgcn_mfma_f32_16x16x32_bf16(Af[0][2], g0, a0, 0, 0, 0);
                a1 = __builtin_amdgcn_mfma_f32_16x16x32_bf16(Af[0][6], g2, a1, 0, 0, 0);
            }
            // retire: relu -> bf16 -> Hf[pb^1] (fragment-order, 4 dwords/bank)
            {
                const int wo = (pb ^ 1) * HFH;
                int2 hv;
                if constexpr (!TWO) a0 += a1;   // merge light chains
                hv.x = (int)pk_hu(fmaxf(a0.x, 0.f), fmaxf(a0.y, 0.f));
                hv.y = (int)pk_hu(fmaxf(a0.z, 0.f), fmaxf(a0.w, 0.f));
                *(int2*)(st0 + wo) = hv;
                if constexpr (TWO) {
                    hv.x = (int)pk_hu(fmaxf(a1.x, 0.f), fmaxf(a1.y, 0.f));
                    hv.y = (int)pk_hu(fmaxf(a1.z, 0.f), fmaxf(a1.w, 0.f));
                    *(int2*)(st1 + wo) = hv;
                }
            }
            // seed next step's x-contribution BEFORE the barrier (x is
            // recurrence-independent; a0/a1 are dead here, so no extra pressure)
            if (s < CH - 1) {
                const s8v xb = *(const s8v*)&Xf[c & 1][s + 1][lane * 8];
                a0 = __builtin_amdgcn_mfma_f32_16x16x32_bf16(Af[0][7], xb, Z, 0, 0, 0);
                if constexpr (TWO)
                    a1 = __builtin_amdgcn_mfma_f32_16x16x32_bf16(Af[1][7], xb, Z, 0, 0, 0);
            } else if (c + 1 < NCH) {
                // next chunk's x: Xf[(c+1)&1] written by prepass at s==4, visible since
                const s8v xb = *(const s8v*)&Xf[(c + 1) & 1][0][lane * 8];
                a0 = __builtin_amdgcn_mfma_f32_16x16x32_bf16(Af[0][7], xb, Z, 0, 0, 0);
                if constexpr (TWO)
                    a1 = __builtin_amdgcn_mfma_f32_16x16x32_bf16(Af[1][7], xb, Z, 0, 0, 0);
            }
            // pipeline plumbing (wave-uniform, compile-time s):
            if (s == 4 && c + 1 < NCH) prepass(c + 1);
            if (s == 5 && c + 2 < NCH) issue_dma(c + 2);
            if (s == 3) VSTEP_BAR();
            else        STEP_BAR();
        }
    };

    #pragma unroll 1
    for (int c = 0; c < NCH; ++c) {
        if (two) chunk(c, BC<true>{});
        else     chunk(c, BC<false>{});
    }

    __syncthreads();
    // ---- FC epilogue: h_T (bf16) in Hf[0] (t=127 wrote pb^1 = 0)
    if (tid < BB * 10) {
        const int o = tid >> 4, r = tid & 15;
        const float* wrow = W_fc + o * HH;
        float acc = b_fc[o];
        #pragma unroll 1
        for (int kb = 0; kb < 25; ++kb) {
            const s8v hv = *(const s8v*)&Hf[0][kb >> 2][(16 * (kb & 3) + r) * 8];
            const f4v w0 = *(const f4v*)(wrow + kb * 8);
            const f4v w1 = *(const f4v*)(wrow + kb * 8 + 4);
            acc = fmaf(bf2f(hv[0]), w0.x, acc);
            acc = fmaf(bf2f(hv[1]), w0.y, acc);
            acc = fmaf(bf2f(hv[2]), w0.z, acc);
            acc = fmaf(bf2f(hv[3]), w0.w, acc);
            acc = fmaf(bf2f(hv[4]), w1.x, acc);
            acc = fmaf(bf2f(hv[5]), w1.y, acc);
            acc = fmaf(bf2f(hv[6]), w1.z, acc);
            acc = fmaf(bf2f(hv[7]), w1.w, acc);
        }
        __builtin_nontemporal_store(acc, &out[(long)(b0 + r) * 10 + o]);
    }
}

extern "C" void kernel_launch(void* const* d_in, const int* in_sizes, int n_in,
                              void* d_out, int out_size, void* d_ws, size_t ws_size,
                              hipStream_t stream) {
    const float* x    = (const float*)d_in[0];
    const float* W_ih = (const float*)d_in[1];
    const float* W_hh = (const float*)d_in[2];
    const float* b_ih = (const float*)d_in[3];
    const float* b_hh = (const float*)d_in[4];
    const float* W_fc = (const float*)d_in[5];
    const float* b_fc = (const float*)d_in[6];
    float* out = (float*)d_out;

    rnn_r13<<<dim3(8192 / BB), dim3(NT), 0, stream>>>(
        x, W_ih, W_hh, b_ih, b_hh, W_fc, b_fc, out);
}